// Round 11
// baseline (101.648 us; speedup 1.0000x reference)
//
#include <hip/hip_runtime.h>
#include <hip/hip_bf16.h>
#include <math.h>

typedef __bf16 bf16x8 __attribute__((ext_vector_type(8)));
typedef float  f32x4  __attribute__((ext_vector_type(4)));

// ---------------- problem constants ----------------
#define BATCH 2
#define SEQ   256
#define DMODL 768
#define DIEXP 1536
#define NHEAD 24
#define HDIM  64
#define NSTATE 64
#define RRANK 2
#define NANG  16
#define HALFSPLIT 32
#define DINP  3416
#define DINP_PAD 3456     // 54*64
#define AFLOOR 1e-4f
#define EPSV   1e-5f

__device__ __forceinline__ float softplusf(float x) {
    if (x > 20.f) return x;
    return log1pf(expf(x));
}
__device__ __forceinline__ float sigmoidf_(float x) {
    return 1.f / (1.f + __expf(-x));
}
__device__ __forceinline__ ushort f2bf(float f) {
    uint u = __float_as_uint(f);
    uint r = (u + 0x7FFFu + ((u >> 16) & 1u)) >> 16;
    return (ushort)r;
}
__device__ __forceinline__ float bf2f(ushort x) {
    uint u = ((uint)x) << 16;
    return __uint_as_float(u);
}

// ---------------- GEMM1: [z|x|B|C|scalars] = u @ in_w^T, routed epilogue --------
// (unchanged from round 10)
__global__ __launch_bounds__(256) void gemm1(const float* __restrict__ A,
        const float* __restrict__ W, ushort* __restrict__ ZT, ushort* __restrict__ XT,
        ushort* __restrict__ BC, float* __restrict__ DTA) {
    const int bm = blockIdx.y * 64, bn = blockIdx.x * 64;
    const int tid = threadIdx.x;
    const int wv = tid >> 6, lane = tid & 63;
    const int wr = (wv >> 1) * 32, wc = (wv & 1) * 32;
    __shared__ ushort As[2][64 * 64];
    __shared__ ushort Bs[2][64 * 64];
    __shared__ ushort Ts[64][72];
    const int srow = tid >> 4, sc4 = tid & 15;
    const int NT = DMODL >> 6;   // 12
    float4 ra[4], rw[4];

    auto load_tile = [&](int t) {
        const int k0 = t * 64;
        #pragma unroll
        for (int p = 0; p < 4; ++p)
            ra[p] = *(const float4*)(A + (size_t)(bm + p * 16 + srow) * DMODL + k0 + sc4 * 4);
        #pragma unroll
        for (int p = 0; p < 4; ++p) {
            int r = p * 16 + srow;
            rw[p] = (bn + r < DINP)
                  ? *(const float4*)(W + (size_t)(bn + r) * DMODL + k0 + sc4 * 4)
                  : (float4){0.f, 0.f, 0.f, 0.f};
        }
    };
    auto write_tile = [&](int buf) {
        #pragma unroll
        for (int p = 0; p < 4; ++p) {
            int r = p * 16 + srow;
            int byt = (sc4 * 8) ^ ((r & 7) << 4);
            ushort4 h;
            h.x = f2bf(ra[p].x); h.y = f2bf(ra[p].y);
            h.z = f2bf(ra[p].z); h.w = f2bf(ra[p].w);
            *(ushort4*)(&As[buf][r * 64 + (byt >> 1)]) = h;
        }
        #pragma unroll
        for (int p = 0; p < 4; ++p) {
            int r = p * 16 + srow;
            int byt = (sc4 * 8) ^ ((r & 7) << 4);
            ushort4 h;
            h.x = f2bf(rw[p].x); h.y = f2bf(rw[p].y);
            h.z = f2bf(rw[p].z); h.w = f2bf(rw[p].w);
            *(ushort4*)(&Bs[buf][r * 64 + (byt >> 1)]) = h;
        }
    };

    f32x4 acc[2][2];
    #pragma unroll
    for (int m = 0; m < 2; ++m)
        #pragma unroll
        for (int n = 0; n < 2; ++n) acc[m][n] = (f32x4){0.f, 0.f, 0.f, 0.f};
    const int fr = lane & 15, fk = (lane >> 4) * 16;

    auto compute = [&](int buf) {
        #pragma unroll
        for (int kk = 0; kk < 2; ++kk) {
            bf16x8 af[2], bff[2];
            #pragma unroll
            for (int m = 0; m < 2; ++m) {
                int r = wr + m * 16 + fr;
                int byt = (kk * 64 + fk) ^ ((r & 7) << 4);
                af[m] = *(const bf16x8*)(&As[buf][r * 64 + (byt >> 1)]);
            }
            #pragma unroll
            for (int n = 0; n < 2; ++n) {
                int r = wc + n * 16 + fr;
                int byt = (kk * 64 + fk) ^ ((r & 7) << 4);
                bff[n] = *(const bf16x8*)(&Bs[buf][r * 64 + (byt >> 1)]);
            }
            #pragma unroll
            for (int m = 0; m < 2; ++m)
                #pragma unroll
                for (int n = 0; n < 2; ++n)
                    acc[m][n] = __builtin_amdgcn_mfma_f32_16x16x32_bf16(af[m], bff[n], acc[m][n], 0, 0, 0);
        }
    };

    load_tile(0);
    write_tile(0);
    __syncthreads();
    for (int t = 0; t < NT; ++t) {
        if (t + 1 < NT) load_tile(t + 1);
        compute(t & 1);
        if (t + 1 < NT) write_tile((t + 1) & 1);
        __syncthreads();
    }

    const int r0 = bm + wr + (lane >> 4) * 4;
    if (bn >= 3328) {
        #pragma unroll
        for (int n = 0; n < 2; ++n) {
            int col = bn + wc + n * 16 + fr;
            #pragma unroll
            for (int m = 0; m < 2; ++m)
                #pragma unroll
                for (int r = 0; r < 4; ++r)
                    DTA[(size_t)(col - 3328) * 512 + r0 + m * 16 + r] = acc[m][n][r];
        }
        return;
    }
    #pragma unroll
    for (int m = 0; m < 2; ++m)
        #pragma unroll
        for (int n = 0; n < 2; ++n)
            #pragma unroll
            for (int r = 0; r < 4; ++r)
                Ts[wr + m * 16 + (lane >> 4) * 4 + r][wc + n * 16 + fr] =
                    f2bf(acc[m][n][r]);
    __syncthreads();
    if (bn < 3072) {
        const bool isX = bn >= 1536;
        const int hh = (bn - (isX ? 1536 : 0)) >> 6;
        const int bb = bm >> 8, l0 = bm & 255;
        ushort* dst = (isX ? XT : ZT);
        const int p = tid >> 2, t0 = (tid & 3) * 16;
        ushort* o = dst + ((size_t)(bb * NHEAD + hh) * HDIM + p) * SEQ + l0 + t0;
        #pragma unroll
        for (int k = 0; k < 16; ++k) o[k] = Ts[t0 + k][p];
    } else {
        const int c0 = bn - 3072;
        const int rr = tid >> 2, cs = (tid & 3) * 16;
        ushort* o = BC + (size_t)(bm + rr) * 256 + c0 + cs;
        #pragma unroll
        for (int k = 0; k < 16; ++k) o[k] = Ts[rr][cs + k];
    }
}

// ---------------- scanprep: scalars + cumsums (theta in LDS) + RMS/RoPE --------
// One block per (b,h); 48 blocks. Also zero-fills d_out for gemm2's atomics.
__global__ __launch_bounds__(256) void scanprep(const float* __restrict__ DTA,
        const ushort* __restrict__ BC, const float* __restrict__ dt_bias,
        const float* __restrict__ Bbias, const float* __restrict__ Cbias,
        const float* __restrict__ Bnw, const float* __restrict__ Cnw,
        float* __restrict__ DTv, float* __restrict__ lamv, float* __restrict__ Pc,
        ushort* __restrict__ Bh, ushort* __restrict__ Ch, float* __restrict__ outZ) {
    const int bh = blockIdx.x;
    const int b = bh / NHEAD, h = bh % NHEAD;
    const int tid = threadIdx.x;
    // zero d_out: 48 blocks x 256 threads x 8 float4 = 98,304 float4 = 512*768 f
    {
        float4* o4 = (float4*)outZ;
        int base = bh * 2048 + tid;
        #pragma unroll
        for (int k = 0; k < 8; ++k) o4[base + k * 256] = (float4){0.f, 0.f, 0.f, 0.f};
    }
    __shared__ float mm[SEQ][18];
    __shared__ float thl[SEQ][NANG];
    const int l = tid;
    const int gl = b * SEQ + l;
    float DT  = softplusf(DTA[(size_t)h * 512 + gl] + dt_bias[h]);
    float Asp = fmaxf(softplusf(DTA[(size_t)(24 + h) * 512 + gl]), AFLOOR);
    float la  = -Asp * DT;
    float lam = sigmoidf_(DTA[(size_t)(48 + h) * 512 + gl]);
    DTv[bh * SEQ + l] = DT;
    lamv[bh * SEQ + l] = lam;
    #pragma unroll
    for (int i = 0; i < NANG; ++i) mm[l][i] = DT * DTA[(size_t)(72 + i) * 512 + gl];
    mm[l][16] = la;
    __syncthreads();
    const int wv = tid >> 6, lane = tid & 63;
    for (int ch = wv; ch < 17; ch += 4) {
        float carry = 0.f;
        for (int seg = 0; seg < 4; ++seg) {
            float v = mm[seg * 64 + lane][ch];
            #pragma unroll
            for (int off = 1; off < 64; off <<= 1) {
                float t = __shfl_up(v, off);
                if (lane >= off) v += t;
            }
            v += carry;
            carry = __shfl(v, 63);
            int ll = seg * 64 + lane;
            if (ch < 16)
                thl[ll][ch] = v;
            else
                Pc[bh * SEQ + ll] = v;
        }
    }
    __syncthreads();
    // phase 2: RMS + bias + RoPE for this h. Wave wv handles l = wv, wv+4, ...
    // lane n = state index; RoPE pair exchanged via shfl_xor(.,1).
    const int n = lane;
    const float bw  = Bnw[n], cw = Cnw[n];
    const float bb0 = Bbias[(h * RRANK + 0) * NSTATE + n];
    const float bb1 = Bbias[(h * RRANK + 1) * NSTATE + n];
    const float cb0 = Cbias[(h * RRANK + 0) * NSTATE + n];
    const float cb1 = Cbias[(h * RRANK + 1) * NSTATE + n];
    for (int ll = wv; ll < SEQ; ll += 4) {
        const ushort* row = BC + (size_t)(b * SEQ + ll) * 256;
        float vB0 = bf2f(row[n]);
        float vB1 = bf2f(row[64 + n]);
        float vC0 = bf2f(row[128 + n]);
        float vC1 = bf2f(row[192 + n]);
        float s0 = vB0 * vB0, s1 = vB1 * vB1, s2 = vC0 * vC0, s3 = vC1 * vC1;
        #pragma unroll
        for (int off = 32; off; off >>= 1) {
            s0 += __shfl_xor(s0, off); s1 += __shfl_xor(s1, off);
            s2 += __shfl_xor(s2, off); s3 += __shfl_xor(s3, off);
        }
        float b0 = vB0 * rsqrtf(s0 / 64.f + EPSV) * bw * bb0;
        float b1 = vB1 * rsqrtf(s1 / 64.f + EPSV) * bw * bb1;
        float c0 = vC0 * rsqrtf(s2 / 64.f + EPSV) * cw * cb0;
        float c1 = vC1 * rsqrtf(s3 / 64.f + EPSV) * cw * cb1;
        // partner values (lane^1) — unconditional to keep shfl convergent
        float pB0 = __shfl_xor(b0, 1), pB1 = __shfl_xor(b1, 1);
        float pC0 = __shfl_xor(c0, 1), pC1 = __shfl_xor(c1, 1);
        float outB0 = b0, outB1 = b1, outC0 = c0, outC1 = c1;
        if (n < HALFSPLIT) {
            float th = thl[ll][n >> 1];
            float sth, cth;
            __sincosf(th, &sth, &cth);
            if ((n & 1) == 0) {   // even: x0' = x0*c - x1*s   (partner = x1)
                outB0 = b0 * cth - pB0 * sth;
                outB1 = b1 * cth - pB1 * sth;
                outC0 = c0 * cth - pC0 * sth;
                outC1 = c1 * cth - pC1 * sth;
            } else {              // odd:  x1' = x0*s + x1*c   (partner = x0)
                outB0 = pB0 * sth + b0 * cth;
                outB1 = pB1 * sth + b1 * cth;
                outC0 = pC0 * sth + c0 * cth;
                outC1 = pC1 * sth + c1 * cth;
            }
        }
        size_t o0 = ((size_t)((b * RRANK + 0) * NHEAD + h) * SEQ + ll) * NSTATE + n;
        size_t o1 = ((size_t)((b * RRANK + 1) * NHEAD + h) * SEQ + ll) * NSTATE + n;
        Bh[o0] = f2bf(outB0);  Bh[o1] = f2bf(outB1);
        Ch[o0] = f2bf(outC0);  Ch[o1] = f2bf(outC1);
    }
}

// ---------------- att2: MFMA scan + fused combine/gate (unchanged) -------------
__global__ __launch_bounds__(256) void att2(const ushort* __restrict__ Bh,
        const ushort* __restrict__ Ch, const ushort* __restrict__ XT,
        const ushort* __restrict__ ZT, const float* __restrict__ Pc,
        const float* __restrict__ DTv, const float* __restrict__ lamv,
        const float* __restrict__ mimo_x, const float* __restrict__ mimo_o,
        const float* __restrict__ Dvec, ushort* __restrict__ Yc) {
    const int bh = blockIdx.x, tt = blockIdx.y;
    const int b = bh / NHEAD, h = bh % NHEAD;
    const int tid = threadIdx.x, wv = tid >> 6, lane = tid & 63;
    __shared__ float Pl[SEQ], u1s[SEQ], u2s[SEQ];
    __shared__ ushort Pld[2][4][16][72];
    for (int t = tid; t < SEQ; t += 256) {
        Pl[t]  = Pc[bh * SEQ + t];
        u1s[t] = DTv[bh * SEQ + t] * lamv[bh * SEQ + t];
        u2s[t] = (t + 1 < SEQ) ? DTv[bh * SEQ + t + 1] * (1.f - lamv[bh * SEQ + t + 1]) : 0.f;
    }
    __syncthreads();
    const int r16 = lane & 15, kg = (lane >> 4) * 8;
    const int trow = tt * 64 + wv * 16;
    const int tr0 = trow + (lane >> 4) * 4;
    const int brh0 = (b * RRANK + 0) * NHEAD + h;
    const int brh1 = (b * RRANK + 1) * NHEAD + h;
    bf16x8 ca[2][2];
    {
        const ushort* cp0 = Ch + ((size_t)brh0 * SEQ + trow + r16) * NSTATE + kg;
        const ushort* cp1 = Ch + ((size_t)brh1 * SEQ + trow + r16) * NSTATE + kg;
        ca[0][0] = *(const bf16x8*)cp0;  ca[0][1] = *(const bf16x8*)(cp0 + 32);
        ca[1][0] = *(const bf16x8*)cp1;  ca[1][1] = *(const bf16x8*)(cp1 + 32);
    }
    f32x4 yacc[2][4];
    #pragma unroll
    for (int r2 = 0; r2 < 2; ++r2)
        #pragma unroll
        for (int pf = 0; pf < 4; ++pf) yacc[r2][pf] = (f32x4){0.f, 0.f, 0.f, 0.f};
    float Pt[4];
    #pragma unroll
    for (int r = 0; r < 4; ++r) Pt[r] = Pl[tr0 + r];
    const float Dh = Dvec[h];

    for (int jt = 0; jt <= tt; ++jt) {
        bf16x8 xf[4][2];
        #pragma unroll
        for (int pf = 0; pf < 4; ++pf) {
            const ushort* xp = XT + ((size_t)bh * HDIM + pf * 16 + r16) * SEQ + jt * 64 + kg;
            xf[pf][0] = *(const bf16x8*)xp;
            xf[pf][1] = *(const bf16x8*)(xp + 32);
        }
        f32x4 g[2][4];
        #pragma unroll
        for (int r2 = 0; r2 < 2; ++r2) {
            const size_t bbase = (size_t)(r2 ? brh1 : brh0) * SEQ;
            #pragma unroll
            for (int nf = 0; nf < 4; ++nf) {
                const ushort* bp = Bh + (bbase + jt * 64 + nf * 16 + r16) * NSTATE + kg;
                bf16x8 b0 = *(const bf16x8*)bp;
                bf16x8 b1 = *(const bf16x8*)(bp + 32);
                f32x4 gg = (f32x4){0.f, 0.f, 0.f, 0.f};
                gg = __builtin_amdgcn_mfma_f32_16x16x32_bf16(ca[r2][0], b0, gg, 0, 0, 0);
                gg = __builtin_amdgcn_mfma_f32_16x16x32_bf16(ca[r2][1], b1, gg, 0, 0, 0);
                g[r2][nf] = gg;
            }
        }
        float w[4][4];
        #pragma unroll
        for (int nf = 0; nf < 4; ++nf) {
            const int j = jt * 64 + nf * 16 + r16;
            const float Pj = Pl[j], v1 = u1s[j], v2 = u2s[j];
            #pragma unroll
            for (int r = 0; r < 4; ++r) {
                const int t = tr0 + r;
                w[nf][r] = (j <= t) ? __expf(Pt[r] - Pj) * (v1 + ((j < t) ? v2 : 0.f)) : 0.f;
            }
        }
        #pragma unroll
        for (int r2 = 0; r2 < 2; ++r2)
            #pragma unroll
            for (int nf = 0; nf < 4; ++nf)
                #pragma unroll
                for (int r = 0; r < 4; ++r)
                    Pld[r2][wv][(lane >> 4) * 4 + r][nf * 16 + r16] = f2bf(g[r2][nf][r] * w[nf][r]);
        #pragma unroll
        for (int r2 = 0; r2 < 2; ++r2) {
            bf16x8 pa0 = *(const bf16x8*)&Pld[r2][wv][r16][kg];
            bf16x8 pa1 = *(const bf16x8*)&Pld[r2][wv][r16][32 + kg];
            #pragma unroll
            for (int pf = 0; pf < 4; ++pf) {
                yacc[r2][pf] = __builtin_amdgcn_mfma_f32_16x16x32_bf16(pa0, xf[pf][0], yacc[r2][pf], 0, 0, 0);
                yacc[r2][pf] = __builtin_amdgcn_mfma_f32_16x16x32_bf16(pa1, xf[pf][1], yacc[r2][pf], 0, 0, 0);
            }
        }
    }
    #pragma unroll
    for (int pf = 0; pf < 4; ++pf) {
        const int p = pf * 16 + r16;
        const float mm0 = mimo_x[(h * RRANK + 0) * HDIM + p] * mimo_o[(h * RRANK + 0) * HDIM + p];
        const float mm1 = mimo_x[(h * RRANK + 1) * HDIM + p] * mimo_o[(h * RRANK + 1) * HDIM + p];
        ushort4 xv4 = *(const ushort4*)&XT[((size_t)bh * HDIM + p) * SEQ + tr0];
        ushort4 zv4 = *(const ushort4*)&ZT[((size_t)bh * HDIM + p) * SEQ + tr0];
        const ushort* xvp = (const ushort*)&xv4;
        const ushort* zvp = (const ushort*)&zv4;
        #pragma unroll
        for (int r = 0; r < 4; ++r) {
            const int t = tr0 + r;
            float xv = bf2f(xvp[r]);
            float zv = bf2f(zvp[r]);
            float y = yacc[0][pf][r] * mm0 + yacc[1][pf][r] * mm1 + Dh * xv;
            y *= zv * sigmoidf_(zv);
            Yc[(size_t)(b * SEQ + t) * DIEXP + h * HDIM + p] = f2bf(y);
        }
    }
}

// ---------------- GEMM2 split-K: out += Yc(bf16) @ out_w^T (atomic) ------------
// d_out is zeroed by scanprep (2 kernels earlier on the same stream).
__global__ __launch_bounds__(256) void gemm2(const ushort* __restrict__ A,
        const float* __restrict__ W, float* __restrict__ out) {
    const int bm = blockIdx.y * 64, bn = blockIdx.x * 64, ks = blockIdx.z;
    const int kbase = ks * 384;
    const int tid = threadIdx.x;
    const int wv = tid >> 6, lane = tid & 63;
    const int wr = (wv >> 1) * 32, wc = (wv & 1) * 32;
    __shared__ ushort As[2][64 * 64];
    __shared__ ushort Bs[2][64 * 64];
    const int srow = tid >> 4, sc4 = tid & 15;
    const int arow = tid >> 3, acol = (tid & 7) * 8;
    const int NT = 6;
    uint4 ra[2];
    float4 rw[4];

    auto load_tile = [&](int t) {
        const int k0 = kbase + t * 64;
        #pragma unroll
        for (int p = 0; p < 2; ++p)
            ra[p] = *(const uint4*)(A + (size_t)(bm + p * 32 + arow) * DIEXP + k0 + acol);
        #pragma unroll
        for (int p = 0; p < 4; ++p)
            rw[p] = *(const float4*)(W + (size_t)(bn + p * 16 + srow) * DIEXP + k0 + sc4 * 4);
    };
    auto write_tile = [&](int buf) {
        #pragma unroll
        for (int p = 0; p < 2; ++p) {
            int r = p * 32 + arow;
            int byt = (acol * 2) ^ ((r & 7) << 4);
            *(uint4*)(&As[buf][r * 64 + (byt >> 1)]) = ra[p];
        }
        #pragma unroll
        for (int p = 0; p < 4; ++p) {
            int r = p * 16 + srow;
            int byt = (sc4 * 8) ^ ((r & 7) << 4);
            ushort4 h;
            h.x = f2bf(rw[p].x); h.y = f2bf(rw[p].y);
            h.z = f2bf(rw[p].z); h.w = f2bf(rw[p].w);
            *(ushort4*)(&Bs[buf][r * 64 + (byt >> 1)]) = h;
        }
    };

    f32x4 acc[2][2];
    #pragma unroll
    for (int m = 0; m < 2; ++m)
        #pragma unroll
        for (int n = 0; n < 2; ++n) acc[m][n] = (f32x4){0.f, 0.f, 0.f, 0.f};
    const int fr = lane & 15, fk = (lane >> 4) * 16;

    auto compute = [&](int buf) {
        #pragma unroll
        for (int kk = 0; kk < 2; ++kk) {
            bf16x8 af[2], bff[2];
            #pragma unroll
            for (int m = 0; m < 2; ++m) {
                int r = wr + m * 16 + fr;
                int byt = (kk * 64 + fk) ^ ((r & 7) << 4);
                af[m] = *(const bf16x8*)(&As[buf][r * 64 + (byt >> 1)]);
            }
            #pragma unroll
            for (int n = 0; n < 2; ++n) {
                int r = wc + n * 16 + fr;
                int byt = (kk * 64 + fk) ^ ((r & 7) << 4);
                bff[n] = *(const bf16x8*)(&Bs[buf][r * 64 + (byt >> 1)]);
            }
            #pragma unroll
            for (int m = 0; m < 2; ++m)
                #pragma unroll
                for (int n = 0; n < 2; ++n)
                    acc[m][n] = __builtin_amdgcn_mfma_f32_16x16x32_bf16(af[m], bff[n], acc[m][n], 0, 0, 0);
        }
    };

    load_tile(0);
    write_tile(0);
    __syncthreads();
    for (int t = 0; t < NT; ++t) {
        if (t + 1 < NT) load_tile(t + 1);
        compute(t & 1);
        if (t + 1 < NT) write_tile((t + 1) & 1);
        __syncthreads();
    }

    const int r0 = bm + wr + (lane >> 4) * 4;
    #pragma unroll
    for (int n = 0; n < 2; ++n) {
        int col = bn + wc + n * 16 + fr;
        #pragma unroll
        for (int m = 0; m < 2; ++m)
            #pragma unroll
            for (int r = 0; r < 4; ++r)
                atomicAdd(&out[(size_t)(r0 + m * 16 + r) * DMODL + col], acc[m][n][r]);
    }
}

// ---------------- launch ----------------
extern "C" void kernel_launch(void* const* d_in, const int* in_sizes, int n_in,
                              void* d_out, int out_size, void* d_ws, size_t ws_size,
                              hipStream_t stream) {
    const float* u        = (const float*)d_in[0];
    const float* in_w     = (const float*)d_in[1];
    const float* dt_bias  = (const float*)d_in[2];
    const float* B_bias   = (const float*)d_in[3];
    const float* C_bias   = (const float*)d_in[4];
    const float* B_norm_w = (const float*)d_in[5];
    const float* C_norm_w = (const float*)d_in[6];
    const float* mimo_x   = (const float*)d_in[7];
    const float* mimo_o   = (const float*)d_in[8];
    const float* Dvec     = (const float*)d_in[9];
    const float* out_w    = (const float*)d_in[10];
    float* out = (float*)d_out;

    // workspace layout (float offsets), full sizes audited:
    //   ZT   [0,        393216)  : 786,432 us
    //   XT   [393216,   786432)  : 786,432 us
    //   BC   [786432,   851968)  : 131,072 us
    //   DTA  [851968,   917504)  : 65,536 f
    //   Bh   [917504,  1703936)  : 1,572,864 us = 786,432 f
    //   Ch   [1703936, 2490368)  : 786,432 f
    //   Pc   [2490368, 2502656)  : 12,288 f
    //   DTv  [2502656, 2514944)  : 12,288 f
    //   lamv [2514944, 2527232)  : 12,288 f
    //   Yc   [2527232, 2920448)  : 786,432 us = 393,216 f   (~11.7 MB total)
    float* ws = (float*)d_ws;
    ushort* ZT    = (ushort*)(ws);
    ushort* XT    = (ushort*)(ws + 393216);
    ushort* BC    = (ushort*)(ws + 786432);
    float*  DTA   = ws + 851968;
    ushort* Bh_bf = (ushort*)(ws + 917504);
    ushort* Ch_bf = (ushort*)(ws + 1703936);
    float*  Pc    = ws + 2490368;
    float*  DTv   = ws + 2502656;
    float*  lamv  = ws + 2514944;
    ushort* Yc_bf = (ushort*)(ws + 2527232);

    // 1) routed projection: ZT/XT (transposed bf16), BC (bf16), DTA (fp32 strip)
    gemm1<<<dim3(DINP_PAD / 64, 8), 256, 0, stream>>>(u, in_w, ZT, XT, BC, DTA);
    // 2) scalars + cumsums (theta LDS-only) + RMS/RoPE -> Bh/Ch; zeroes d_out
    scanprep<<<BATCH * NHEAD, 256, 0, stream>>>(DTA, BC, dt_bias, B_bias, C_bias,
                                                B_norm_w, C_norm_w, DTv, lamv, Pc,
                                                Bh_bf, Ch_bf, out);
    // 3) MFMA scan + fused combine -> bf16 Yc
    att2<<<dim3(BATCH * NHEAD, 4), 256, 0, stream>>>(Bh_bf, Ch_bf, XT, ZT, Pc, DTv,
                                                     lamv, mimo_x, mimo_o, Dvec, Yc_bf);
    // 4) split-K GEMM2, atomic accumulate into d_out
    gemm2<<<dim3(DMODL / 64, 8, 4), 256, 0, stream>>>(Yc_bf, out_w, out);
}

// Round 12
// 64.727 us; speedup vs baseline: 1.5704x; 1.5704x over previous
//
#include <hip/hip_runtime.h>
#include <hip/hip_bf16.h>
#include <math.h>

typedef __bf16 bf16x8 __attribute__((ext_vector_type(8)));
typedef float  f32x4  __attribute__((ext_vector_type(4)));

// ---------------- problem constants ----------------
#define BATCH 2
#define SEQ   256
#define DMODL 768
#define DIEXP 1536
#define NHEAD 24
#define HDIM  64
#define NSTATE 64
#define RRANK 2
#define NANG  16
#define HALFSPLIT 32
#define DINP  3416
#define DINP_PAD 3456     // 54*64
#define AFLOOR 1e-4f
#define EPSV   1e-5f

__device__ __forceinline__ float softplusf(float x) {
    if (x > 20.f) return x;
    return log1pf(expf(x));
}
__device__ __forceinline__ float sigmoidf_(float x) {
    return 1.f / (1.f + __expf(-x));
}
__device__ __forceinline__ ushort f2bf(float f) {
    uint u = __float_as_uint(f);
    uint r = (u + 0x7FFFu + ((u >> 16) & 1u)) >> 16;
    return (ushort)r;
}
__device__ __forceinline__ float bf2f(ushort x) {
    uint u = ((uint)x) << 16;
    return __uint_as_float(u);
}

// ---------------- GEMM1: [z|x|B|C|scalars] = u @ in_w^T, routed epilogue --------
__global__ __launch_bounds__(256) void gemm1(const float* __restrict__ A,
        const float* __restrict__ W, ushort* __restrict__ ZT, ushort* __restrict__ XT,
        ushort* __restrict__ BC, float* __restrict__ DTA) {
    const int bm = blockIdx.y * 64, bn = blockIdx.x * 64;
    const int tid = threadIdx.x;
    const int wv = tid >> 6, lane = tid & 63;
    const int wr = (wv >> 1) * 32, wc = (wv & 1) * 32;
    __shared__ ushort As[2][64 * 64];
    __shared__ ushort Bs[2][64 * 64];
    __shared__ ushort Ts[64][72];
    const int srow = tid >> 4, sc4 = tid & 15;
    const int NT = DMODL >> 6;   // 12
    float4 ra[4], rw[4];

    auto load_tile = [&](int t) {
        const int k0 = t * 64;
        #pragma unroll
        for (int p = 0; p < 4; ++p)
            ra[p] = *(const float4*)(A + (size_t)(bm + p * 16 + srow) * DMODL + k0 + sc4 * 4);
        #pragma unroll
        for (int p = 0; p < 4; ++p) {
            int r = p * 16 + srow;
            rw[p] = (bn + r < DINP)
                  ? *(const float4*)(W + (size_t)(bn + r) * DMODL + k0 + sc4 * 4)
                  : (float4){0.f, 0.f, 0.f, 0.f};
        }
    };
    auto write_tile = [&](int buf) {
        #pragma unroll
        for (int p = 0; p < 4; ++p) {
            int r = p * 16 + srow;
            int byt = (sc4 * 8) ^ ((r & 7) << 4);
            ushort4 h;
            h.x = f2bf(ra[p].x); h.y = f2bf(ra[p].y);
            h.z = f2bf(ra[p].z); h.w = f2bf(ra[p].w);
            *(ushort4*)(&As[buf][r * 64 + (byt >> 1)]) = h;
        }
        #pragma unroll
        for (int p = 0; p < 4; ++p) {
            int r = p * 16 + srow;
            int byt = (sc4 * 8) ^ ((r & 7) << 4);
            ushort4 h;
            h.x = f2bf(rw[p].x); h.y = f2bf(rw[p].y);
            h.z = f2bf(rw[p].z); h.w = f2bf(rw[p].w);
            *(ushort4*)(&Bs[buf][r * 64 + (byt >> 1)]) = h;
        }
    };

    f32x4 acc[2][2];
    #pragma unroll
    for (int m = 0; m < 2; ++m)
        #pragma unroll
        for (int n = 0; n < 2; ++n) acc[m][n] = (f32x4){0.f, 0.f, 0.f, 0.f};
    const int fr = lane & 15, fk = (lane >> 4) * 16;

    auto compute = [&](int buf) {
        #pragma unroll
        for (int kk = 0; kk < 2; ++kk) {
            bf16x8 af[2], bff[2];
            #pragma unroll
            for (int m = 0; m < 2; ++m) {
                int r = wr + m * 16 + fr;
                int byt = (kk * 64 + fk) ^ ((r & 7) << 4);
                af[m] = *(const bf16x8*)(&As[buf][r * 64 + (byt >> 1)]);
            }
            #pragma unroll
            for (int n = 0; n < 2; ++n) {
                int r = wc + n * 16 + fr;
                int byt = (kk * 64 + fk) ^ ((r & 7) << 4);
                bff[n] = *(const bf16x8*)(&Bs[buf][r * 64 + (byt >> 1)]);
            }
            #pragma unroll
            for (int m = 0; m < 2; ++m)
                #pragma unroll
                for (int n = 0; n < 2; ++n)
                    acc[m][n] = __builtin_amdgcn_mfma_f32_16x16x32_bf16(af[m], bff[n], acc[m][n], 0, 0, 0);
        }
    };

    load_tile(0);
    write_tile(0);
    __syncthreads();
    for (int t = 0; t < NT; ++t) {
        if (t + 1 < NT) load_tile(t + 1);
        compute(t & 1);
        if (t + 1 < NT) write_tile((t + 1) & 1);
        __syncthreads();
    }

    const int r0 = bm + wr + (lane >> 4) * 4;
    if (bn >= 3328) {
        #pragma unroll
        for (int n = 0; n < 2; ++n) {
            int col = bn + wc + n * 16 + fr;
            #pragma unroll
            for (int m = 0; m < 2; ++m)
                #pragma unroll
                for (int r = 0; r < 4; ++r)
                    DTA[(size_t)(col - 3328) * 512 + r0 + m * 16 + r] = acc[m][n][r];
        }
        return;
    }
    #pragma unroll
    for (int m = 0; m < 2; ++m)
        #pragma unroll
        for (int n = 0; n < 2; ++n)
            #pragma unroll
            for (int r = 0; r < 4; ++r)
                Ts[wr + m * 16 + (lane >> 4) * 4 + r][wc + n * 16 + fr] =
                    f2bf(acc[m][n][r]);
    __syncthreads();
    if (bn < 3072) {
        const bool isX = bn >= 1536;
        const int hh = (bn - (isX ? 1536 : 0)) >> 6;
        const int bb = bm >> 8, l0 = bm & 255;
        ushort* dst = (isX ? XT : ZT);
        const int p = tid >> 2, t0 = (tid & 3) * 16;
        ushort* o = dst + ((size_t)(bb * NHEAD + hh) * HDIM + p) * SEQ + l0 + t0;
        #pragma unroll
        for (int k = 0; k < 16; ++k) o[k] = Ts[t0 + k][p];
    } else {
        const int c0 = bn - 3072;
        const int rr = tid >> 2, cs = (tid & 3) * 16;
        ushort* o = BC + (size_t)(bm + rr) * 256 + c0 + cs;
        #pragma unroll
        for (int k = 0; k < 16; ++k) o[k] = Ts[rr][cs + k];
    }
}

// ---------------- scan: scalars + wave-parallel cumsums; zeroes d_out ----------
__global__ __launch_bounds__(256) void scan_kernel(const float* __restrict__ DTA,
        const float* __restrict__ dt_bias, float* __restrict__ DTv,
        float* __restrict__ lamv, float* __restrict__ Pc, float* __restrict__ theta,
        float* __restrict__ outZ) {
    const int bh = blockIdx.x;
    const int b = bh / NHEAD, h = bh % NHEAD;
    const int tid = threadIdx.x;
    // zero d_out: 48 blocks x 256 threads x 8 float4 = 98,304 float4 = 512*768 f
    {
        float4* o4 = (float4*)outZ;
        int base = bh * 2048 + tid;
        #pragma unroll
        for (int k = 0; k < 8; ++k) o4[base + k * 256] = (float4){0.f, 0.f, 0.f, 0.f};
    }
    __shared__ float mm[SEQ][18];
    const int l = tid;
    const int gl = b * SEQ + l;
    float DT  = softplusf(DTA[(size_t)h * 512 + gl] + dt_bias[h]);
    float Asp = fmaxf(softplusf(DTA[(size_t)(24 + h) * 512 + gl]), AFLOOR);
    float la  = -Asp * DT;
    float lam = sigmoidf_(DTA[(size_t)(48 + h) * 512 + gl]);
    DTv[bh * SEQ + l] = DT;
    lamv[bh * SEQ + l] = lam;
    #pragma unroll
    for (int i = 0; i < NANG; ++i) mm[l][i] = DT * DTA[(size_t)(72 + i) * 512 + gl];
    mm[l][16] = la;
    __syncthreads();
    const int wv = tid >> 6, lane = tid & 63;
    for (int ch = wv; ch < 17; ch += 4) {
        float carry = 0.f;
        for (int seg = 0; seg < 4; ++seg) {
            float v = mm[seg * 64 + lane][ch];
            #pragma unroll
            for (int off = 1; off < 64; off <<= 1) {
                float t = __shfl_up(v, off);
                if (lane >= off) v += t;
            }
            v += carry;
            carry = __shfl(v, 63);
            int ll = seg * 64 + lane;
            if (ch < 16)
                theta[((size_t)(b * SEQ + ll) * NHEAD + h) * NANG + ch] = v;
            else
                Pc[bh * SEQ + ll] = v;
        }
    }
}

// ---------------- prep3: RMS-norm + bias + RoPE -> bf16 Bh, Ch (from BC) --------
__global__ __launch_bounds__(256) void prep3(const ushort* __restrict__ BC,
        const float* __restrict__ Bbias, const float* __restrict__ Cbias,
        const float* __restrict__ Bnw, const float* __restrict__ Cnw,
        const float* __restrict__ theta,
        ushort* __restrict__ Bh, ushort* __restrict__ Ch) {
    int bl = blockIdx.x;
    int b = bl / SEQ, l = bl % SEQ;
    int tid = threadIdx.x;
    __shared__ float sB[RRANK][NSTATE], sC[RRANK][NSTATE], scale[4];
    __shared__ float thl[NHEAD * NANG];
    const ushort* row = BC + (size_t)bl * 256;
    if (tid < 128) {
        int r = tid / 64, n = tid % 64;
        sB[r][n] = bf2f(row[r * 64 + n]);
    } else {
        int t2 = tid - 128;
        int r = t2 / 64, n = t2 % 64;
        sC[r][n] = bf2f(row[128 + r * 64 + n]);
    }
    for (int k = tid; k < NHEAD * NANG; k += 256)
        thl[k] = theta[(size_t)bl * NHEAD * NANG + k];
    __syncthreads();
    int g = tid / 64, lane = tid % 64;
    float v = (g < 2) ? sB[g][lane] : sC[g - 2][lane];
    float ss = v * v;
    #pragma unroll
    for (int off = 32; off; off >>= 1) ss += __shfl_xor(ss, off);
    if (lane == 0) scale[g] = rsqrtf(ss / NSTATE + EPSV);
    __syncthreads();
    float scB[2] = {scale[0], scale[1]};
    float scC[2] = {scale[2], scale[3]};
    for (int idx = tid; idx < RRANK * NHEAD * NSTATE; idx += 256) {
        int n = idx % NSTATE;
        int h = (idx / NSTATE) % NHEAD;
        int r = idx / (NSTATE * NHEAD);
        float outB, outC;
        if (n < HALFSPLIT) {
            int i = n >> 1;
            int n0 = i * 2, n1 = n0 + 1;
            float th = thl[h * NANG + i];
            float c, s;
            __sincosf(th, &s, &c);
            float b0 = sB[r][n0] * scB[r] * Bnw[n0] * Bbias[(h * RRANK + r) * NSTATE + n0];
            float b1 = sB[r][n1] * scB[r] * Bnw[n1] * Bbias[(h * RRANK + r) * NSTATE + n1];
            float c0 = sC[r][n0] * scC[r] * Cnw[n0] * Cbias[(h * RRANK + r) * NSTATE + n0];
            float c1 = sC[r][n1] * scC[r] * Cnw[n1] * Cbias[(h * RRANK + r) * NSTATE + n1];
            outB = (n & 1) ? (b0 * s + b1 * c) : (b0 * c - b1 * s);
            outC = (n & 1) ? (c0 * s + c1 * c) : (c0 * c - c1 * s);
        } else {
            outB = sB[r][n] * scB[r] * Bnw[n] * Bbias[(h * RRANK + r) * NSTATE + n];
            outC = sC[r][n] * scC[r] * Cnw[n] * Cbias[(h * RRANK + r) * NSTATE + n];
        }
        size_t o = ((size_t)((b * RRANK + r) * NHEAD + h) * SEQ + l) * NSTATE + n;
        Bh[o] = f2bf(outB);
        Ch[o] = f2bf(outC);
    }
}

// ---------------- att2: MFMA scan + fused combine/gate (unchanged) -------------
__global__ __launch_bounds__(256) void att2(const ushort* __restrict__ Bh,
        const ushort* __restrict__ Ch, const ushort* __restrict__ XT,
        const ushort* __restrict__ ZT, const float* __restrict__ Pc,
        const float* __restrict__ DTv, const float* __restrict__ lamv,
        const float* __restrict__ mimo_x, const float* __restrict__ mimo_o,
        const float* __restrict__ Dvec, ushort* __restrict__ Yc) {
    const int bh = blockIdx.x, tt = blockIdx.y;
    const int b = bh / NHEAD, h = bh % NHEAD;
    const int tid = threadIdx.x, wv = tid >> 6, lane = tid & 63;
    __shared__ float Pl[SEQ], u1s[SEQ], u2s[SEQ];
    __shared__ ushort Pld[2][4][16][72];
    for (int t = tid; t < SEQ; t += 256) {
        Pl[t]  = Pc[bh * SEQ + t];
        u1s[t] = DTv[bh * SEQ + t] * lamv[bh * SEQ + t];
        u2s[t] = (t + 1 < SEQ) ? DTv[bh * SEQ + t + 1] * (1.f - lamv[bh * SEQ + t + 1]) : 0.f;
    }
    __syncthreads();
    const int r16 = lane & 15, kg = (lane >> 4) * 8;
    const int trow = tt * 64 + wv * 16;
    const int tr0 = trow + (lane >> 4) * 4;
    const int brh0 = (b * RRANK + 0) * NHEAD + h;
    const int brh1 = (b * RRANK + 1) * NHEAD + h;
    bf16x8 ca[2][2];
    {
        const ushort* cp0 = Ch + ((size_t)brh0 * SEQ + trow + r16) * NSTATE + kg;
        const ushort* cp1 = Ch + ((size_t)brh1 * SEQ + trow + r16) * NSTATE + kg;
        ca[0][0] = *(const bf16x8*)cp0;  ca[0][1] = *(const bf16x8*)(cp0 + 32);
        ca[1][0] = *(const bf16x8*)cp1;  ca[1][1] = *(const bf16x8*)(cp1 + 32);
    }
    f32x4 yacc[2][4];
    #pragma unroll
    for (int r2 = 0; r2 < 2; ++r2)
        #pragma unroll
        for (int pf = 0; pf < 4; ++pf) yacc[r2][pf] = (f32x4){0.f, 0.f, 0.f, 0.f};
    float Pt[4];
    #pragma unroll
    for (int r = 0; r < 4; ++r) Pt[r] = Pl[tr0 + r];
    const float Dh = Dvec[h];

    for (int jt = 0; jt <= tt; ++jt) {
        bf16x8 xf[4][2];
        #pragma unroll
        for (int pf = 0; pf < 4; ++pf) {
            const ushort* xp = XT + ((size_t)bh * HDIM + pf * 16 + r16) * SEQ + jt * 64 + kg;
            xf[pf][0] = *(const bf16x8*)xp;
            xf[pf][1] = *(const bf16x8*)(xp + 32);
        }
        f32x4 g[2][4];
        #pragma unroll
        for (int r2 = 0; r2 < 2; ++r2) {
            const size_t bbase = (size_t)(r2 ? brh1 : brh0) * SEQ;
            #pragma unroll
            for (int nf = 0; nf < 4; ++nf) {
                const ushort* bp = Bh + (bbase + jt * 64 + nf * 16 + r16) * NSTATE + kg;
                bf16x8 b0 = *(const bf16x8*)bp;
                bf16x8 b1 = *(const bf16x8*)(bp + 32);
                f32x4 gg = (f32x4){0.f, 0.f, 0.f, 0.f};
                gg = __builtin_amdgcn_mfma_f32_16x16x32_bf16(ca[r2][0], b0, gg, 0, 0, 0);
                gg = __builtin_amdgcn_mfma_f32_16x16x32_bf16(ca[r2][1], b1, gg, 0, 0, 0);
                g[r2][nf] = gg;
            }
        }
        float w[4][4];
        #pragma unroll
        for (int nf = 0; nf < 4; ++nf) {
            const int j = jt * 64 + nf * 16 + r16;
            const float Pj = Pl[j], v1 = u1s[j], v2 = u2s[j];
            #pragma unroll
            for (int r = 0; r < 4; ++r) {
                const int t = tr0 + r;
                w[nf][r] = (j <= t) ? __expf(Pt[r] - Pj) * (v1 + ((j < t) ? v2 : 0.f)) : 0.f;
            }
        }
        #pragma unroll
        for (int r2 = 0; r2 < 2; ++r2)
            #pragma unroll
            for (int nf = 0; nf < 4; ++nf)
                #pragma unroll
                for (int r = 0; r < 4; ++r)
                    Pld[r2][wv][(lane >> 4) * 4 + r][nf * 16 + r16] = f2bf(g[r2][nf][r] * w[nf][r]);
        #pragma unroll
        for (int r2 = 0; r2 < 2; ++r2) {
            bf16x8 pa0 = *(const bf16x8*)&Pld[r2][wv][r16][kg];
            bf16x8 pa1 = *(const bf16x8*)&Pld[r2][wv][r16][32 + kg];
            #pragma unroll
            for (int pf = 0; pf < 4; ++pf) {
                yacc[r2][pf] = __builtin_amdgcn_mfma_f32_16x16x32_bf16(pa0, xf[pf][0], yacc[r2][pf], 0, 0, 0);
                yacc[r2][pf] = __builtin_amdgcn_mfma_f32_16x16x32_bf16(pa1, xf[pf][1], yacc[r2][pf], 0, 0, 0);
            }
        }
    }
    #pragma unroll
    for (int pf = 0; pf < 4; ++pf) {
        const int p = pf * 16 + r16;
        const float mm0 = mimo_x[(h * RRANK + 0) * HDIM + p] * mimo_o[(h * RRANK + 0) * HDIM + p];
        const float mm1 = mimo_x[(h * RRANK + 1) * HDIM + p] * mimo_o[(h * RRANK + 1) * HDIM + p];
        ushort4 xv4 = *(const ushort4*)&XT[((size_t)bh * HDIM + p) * SEQ + tr0];
        ushort4 zv4 = *(const ushort4*)&ZT[((size_t)bh * HDIM + p) * SEQ + tr0];
        const ushort* xvp = (const ushort*)&xv4;
        const ushort* zvp = (const ushort*)&zv4;
        #pragma unroll
        for (int r = 0; r < 4; ++r) {
            const int t = tr0 + r;
            float xv = bf2f(xvp[r]);
            float zv = bf2f(zvp[r]);
            float y = yacc[0][pf][r] * mm0 + yacc[1][pf][r] * mm1 + Dh * xv;
            y *= zv * sigmoidf_(zv);
            Yc[(size_t)(b * SEQ + t) * DIEXP + h * HDIM + p] = f2bf(y);
        }
    }
}

// ---------------- GEMM2 split-K: out += Yc(bf16) @ out_w^T (atomic) ------------
// d_out is zeroed by scan_kernel (3 kernels earlier on the same stream).
__global__ __launch_bounds__(256) void gemm2(const ushort* __restrict__ A,
        const float* __restrict__ W, float* __restrict__ out) {
    const int bm = blockIdx.y * 64, bn = blockIdx.x * 64, ks = blockIdx.z;
    const int kbase = ks * 384;
    const int tid = threadIdx.x;
    const int wv = tid >> 6, lane = tid & 63;
    const int wr = (wv >> 1) * 32, wc = (wv & 1) * 32;
    __shared__ ushort As[2][64 * 64];
    __shared__ ushort Bs[2][64 * 64];
    const int srow = tid >> 4, sc4 = tid & 15;
    const int arow = tid >> 3, acol = (tid & 7) * 8;
    const int NT = 6;
    uint4 ra[2];
    float4 rw[4];

    auto load_tile = [&](int t) {
        const int k0 = kbase + t * 64;
        #pragma unroll
        for (int p = 0; p < 2; ++p)
            ra[p] = *(const uint4*)(A + (size_t)(bm + p * 32 + arow) * DIEXP + k0 + acol);
        #pragma unroll
        for (int p = 0; p < 4; ++p)
            rw[p] = *(const float4*)(W + (size_t)(bn + p * 16 + srow) * DIEXP + k0 + sc4 * 4);
    };
    auto write_tile = [&](int buf) {
        #pragma unroll
        for (int p = 0; p < 2; ++p) {
            int r = p * 32 + arow;
            int byt = (acol * 2) ^ ((r & 7) << 4);
            *(uint4*)(&As[buf][r * 64 + (byt >> 1)]) = ra[p];
        }
        #pragma unroll
        for (int p = 0; p < 4; ++p) {
            int r = p * 16 + srow;
            int byt = (sc4 * 8) ^ ((r & 7) << 4);
            ushort4 h;
            h.x = f2bf(rw[p].x); h.y = f2bf(rw[p].y);
            h.z = f2bf(rw[p].z); h.w = f2bf(rw[p].w);
            *(ushort4*)(&Bs[buf][r * 64 + (byt >> 1)]) = h;
        }
    };

    f32x4 acc[2][2];
    #pragma unroll
    for (int m = 0; m < 2; ++m)
        #pragma unroll
        for (int n = 0; n < 2; ++n) acc[m][n] = (f32x4){0.f, 0.f, 0.f, 0.f};
    const int fr = lane & 15, fk = (lane >> 4) * 16;

    auto compute = [&](int buf) {
        #pragma unroll
        for (int kk = 0; kk < 2; ++kk) {
            bf16x8 af[2], bff[2];
            #pragma unroll
            for (int m = 0; m < 2; ++m) {
                int r = wr + m * 16 + fr;
                int byt = (kk * 64 + fk) ^ ((r & 7) << 4);
                af[m] = *(const bf16x8*)(&As[buf][r * 64 + (byt >> 1)]);
            }
            #pragma unroll
            for (int n = 0; n < 2; ++n) {
                int r = wc + n * 16 + fr;
                int byt = (kk * 64 + fk) ^ ((r & 7) << 4);
                bff[n] = *(const bf16x8*)(&Bs[buf][r * 64 + (byt >> 1)]);
            }
            #pragma unroll
            for (int m = 0; m < 2; ++m)
                #pragma unroll
                for (int n = 0; n < 2; ++n)
                    acc[m][n] = __builtin_amdgcn_mfma_f32_16x16x32_bf16(af[m], bff[n], acc[m][n], 0, 0, 0);
        }
    };

    load_tile(0);
    write_tile(0);
    __syncthreads();
    for (int t = 0; t < NT; ++t) {
        if (t + 1 < NT) load_tile(t + 1);
        compute(t & 1);
        if (t + 1 < NT) write_tile((t + 1) & 1);
        __syncthreads();
    }

    const int r0 = bm + wr + (lane >> 4) * 4;
    #pragma unroll
    for (int n = 0; n < 2; ++n) {
        int col = bn + wc + n * 16 + fr;
        #pragma unroll
        for (int m = 0; m < 2; ++m)
            #pragma unroll
            for (int r = 0; r < 4; ++r)
                atomicAdd(&out[(size_t)(r0 + m * 16 + r) * DMODL + col], acc[m][n][r]);
    }
}

// ---------------- launch ----------------
extern "C" void kernel_launch(void* const* d_in, const int* in_sizes, int n_in,
                              void* d_out, int out_size, void* d_ws, size_t ws_size,
                              hipStream_t stream) {
    const float* u        = (const float*)d_in[0];
    const float* in_w     = (const float*)d_in[1];
    const float* dt_bias  = (const float*)d_in[2];
    const float* B_bias   = (const float*)d_in[3];
    const float* C_bias   = (const float*)d_in[4];
    const float* B_norm_w = (const float*)d_in[5];
    const float* C_norm_w = (const float*)d_in[6];
    const float* mimo_x   = (const float*)d_in[7];
    const float* mimo_o   = (const float*)d_in[8];
    const float* Dvec     = (const float*)d_in[9];
    const float* out_w    = (const float*)d_in[10];
    float* out = (float*)d_out;

    // workspace layout (float offsets), full sizes audited:
    //   ZT   [0,        393216)  : 786,432 us
    //   XT   [393216,   786432)  : 786,432 us
    //   BC   [786432,   851968)  : 131,072 us
    //   DTA  [851968,   917504)  : 65,536 f
    //   Bh   [917504,  1703936)  : 1,572,864 us = 786,432 f
    //   Ch   [1703936, 2490368)  : 786,432 f
    //   theta[2490368, 2686976)  : 196,608 f
    //   Pc   [2686976, 2699264)  : 12,288 f
    //   DTv  [2699264, 2711552)  : 12,288 f
    //   lamv [2711552, 2723840)  : 12,288 f
    //   Yc   [2723840, 3117056)  : 786,432 us = 393,216 f   (~12.5 MB total)
    float* ws = (float*)d_ws;
    ushort* ZT    = (ushort*)(ws);
    ushort* XT    = (ushort*)(ws + 393216);
    ushort* BC    = (ushort*)(ws + 786432);
    float*  DTA   = ws + 851968;
    ushort* Bh_bf = (ushort*)(ws + 917504);
    ushort* Ch_bf = (ushort*)(ws + 1703936);
    float*  theta = ws + 2490368;
    float*  Pc    = ws + 2686976;
    float*  DTv   = ws + 2699264;
    float*  lamv  = ws + 2711552;
    ushort* Yc_bf = (ushort*)(ws + 2723840);

    // 1) routed projection: ZT/XT (transposed bf16), BC (bf16), DTA (fp32 strip)
    gemm1<<<dim3(DINP_PAD / 64, 8), 256, 0, stream>>>(u, in_w, ZT, XT, BC, DTA);
    // 2) scalars + wave-parallel cumsums (P, theta); zeroes d_out
    scan_kernel<<<BATCH * NHEAD, 256, 0, stream>>>(DTA, dt_bias, DTv, lamv, Pc,
                                                   theta, out);
    // 3) RMS + bias + RoPE -> bf16 Bh/Ch
    prep3<<<BATCH * SEQ, 256, 0, stream>>>(BC, B_bias, C_bias, B_norm_w, C_norm_w,
                                           theta, Bh_bf, Ch_bf);
    // 4) MFMA scan + fused combine -> bf16 Yc
    att2<<<dim3(BATCH * NHEAD, 4), 256, 0, stream>>>(Bh_bf, Ch_bf, XT, ZT, Pc, DTv,
                                                     lamv, mimo_x, mimo_o, Dvec, Yc_bf);
    // 5) split-K GEMM2, atomic accumulate into d_out
    gemm2<<<dim3(DMODL / 64, 8, 4), 256, 0, stream>>>(Yc_bf, out_w, out);
}